// Round 3
// baseline (849.532 us; speedup 1.0000x reference)
//
#include <hip/hip_runtime.h>
#include <math.h>

#define H 1024
#define V 32000
#define L 4096
#define NBLK 256
#define NTHR 512
#define APITCH 72

typedef __bf16 bf16x8 __attribute__((ext_vector_type(8)));
typedef float f32x4 __attribute__((ext_vector_type(4)));

__device__ __forceinline__ unsigned short f32_to_bf16(float f) {
    unsigned int u = __float_as_uint(f);
    unsigned int r = (u + 0x7fffu + ((u >> 16) & 1u)) >> 16;
    return (unsigned short)r;
}

__device__ __forceinline__ float bf16_to_f32(unsigned short s) {
    return __uint_as_float(((unsigned int)s) << 16);
}

__device__ __forceinline__ float dot4(float4 a, float4 b) {
    return a.x * b.x + a.y * b.y + a.z * b.z + a.w * b.w;
}

__device__ __forceinline__ float wave_reduce(float v) {
    for (int off = 32; off; off >>= 1) v += __shfl_xor(v, off);
    return v;
}

// Grid barrier for NBLK co-resident blocks (1 block/CU, 256 blocks on 256
// CUs -> residency by construction). Release fence + agent-scope atomic
// arrive + spin on generation + acquire fence. 5 ms s_memrealtime timeout
// (100 MHz => 500000 ticks) makes any residual scheduling surprise fail
// gracefully (wrong results, terminating) instead of hanging the container.
__device__ __forceinline__ void grid_sync(unsigned* bar) {
    __threadfence();
    __syncthreads();
    if (threadIdx.x == 0) {
        unsigned g = __hip_atomic_load(&bar[1], __ATOMIC_RELAXED, __HIP_MEMORY_SCOPE_AGENT);
        unsigned a = __hip_atomic_fetch_add(&bar[0], 1u, __ATOMIC_ACQ_REL, __HIP_MEMORY_SCOPE_AGENT);
        if (a == NBLK - 1u) {
            __hip_atomic_store(&bar[0], 0u, __ATOMIC_RELAXED, __HIP_MEMORY_SCOPE_AGENT);
            __hip_atomic_store(&bar[1], g + 1u, __ATOMIC_RELEASE, __HIP_MEMORY_SCOPE_AGENT);
        } else {
            unsigned long long t0 = __builtin_amdgcn_s_memrealtime();
            while (__hip_atomic_load(&bar[1], __ATOMIC_ACQUIRE, __HIP_MEMORY_SCOPE_AGENT) == g) {
                __builtin_amdgcn_s_sleep(4);
                if (__builtin_amdgcn_s_memrealtime() - t0 > 500000ull) break;
            }
        }
    }
    __syncthreads();
    __threadfence();
}

// 256 blocks x 512 threads (8 waves), 1 block/CU, 6 stages, 5 grid syncs.
__global__ __launch_bounds__(NTHR, 2) void mega_kernel(
        const int* __restrict__ token,
        const float* __restrict__ hidden,
        const float* __restrict__ enc,
        const float* __restrict__ emb,
        const float* __restrict__ wW,
        const float* __restrict__ wb,
        const float* __restrict__ uW,
        const float* __restrict__ ub,
        const float* __restrict__ vW,
        const float* __restrict__ cW,
        const float* __restrict__ cb,
        const float* __restrict__ w_ih,
        const float* __restrict__ b_ih,
        const float* __restrict__ w_hh,
        const float* __restrict__ b_hh,
        const float* __restrict__ outW,
        const float* __restrict__ outb,
        float* __restrict__ out,
        unsigned* __restrict__ bar,
        float* __restrict__ wh,
        float* __restrict__ gh,       // 3H: r, z, n gate pre-activations from hprev
        float* __restrict__ scores,
        float* __restrict__ context,
        float* __restrict__ xvec,
        float* __restrict__ ovec,
        unsigned short* __restrict__ enc_bf,
        unsigned short* __restrict__ u_bf) {
    __shared__ unsigned short Als[128 * APITCH];
    __shared__ unsigned short Bls[128 * APITCH];
    __shared__ float smax[8];
    __shared__ float ssum[8];
    __shared__ float attn_l[32];

    const int tid = threadIdx.x;
    const int blk = blockIdx.x;
    const int gt = blk * NTHR + tid;
    const int wid = tid >> 6, lane = tid & 63;
    const int gw = gt >> 6;   // global wave id, 0..2047

    // ---------------- stage 0: bf16 conversions, zeroing, wh + gh GEMVs --
    {
        const int GSZ = NBLK * NTHR;          // 131072 threads
        const int NE = L * H / 4;
        for (int i = gt; i < NE; i += GSZ) {
            float4 f = ((const float4*)enc)[i];
            ushort4 o;
            o.x = f32_to_bf16(f.x); o.y = f32_to_bf16(f.y);
            o.z = f32_to_bf16(f.z); o.w = f32_to_bf16(f.w);
            ((ushort4*)enc_bf)[i] = o;
        }
        const int NU = H * H / 4;
        for (int i = gt; i < NU; i += GSZ) {
            float4 f = ((const float4*)uW)[i];
            ushort4 o;
            o.x = f32_to_bf16(f.x); o.y = f32_to_bf16(f.y);
            o.z = f32_to_bf16(f.z); o.w = f32_to_bf16(f.w);
            ((ushort4*)u_bf)[i] = o;
        }
        if (gt < L / 4) ((float4*)scores)[gt] = make_float4(0.f, 0.f, 0.f, 0.f);
        else if (gt < L / 4 + H / 4)
            ((float4*)context)[gt - L / 4] = make_float4(0.f, 0.f, 0.f, 0.f);
        if (gw < H) {
            // wh[j] = wW[j,:].h0 + wb[j] + ub[j]
            const float4* row = (const float4*)(wW + (size_t)gw * H);
            const float4* hv = (const float4*)hidden;
            float acc = 0.f;
#pragma unroll
            for (int i = 0; i < 4; i++) {
                int idx = i * 64 + lane;
                acc += dot4(row[idx], hv[idx]);
            }
            acc = wave_reduce(acc);
            if (lane == 0) wh[gw] = acc + wb[gw] + ub[gw];
        } else {
            // gh gates from hprev (independent of attention path)
            int j = gw - H;
            const float4* hv = (const float4*)hidden;
            float a3 = 0.f, a4 = 0.f, a5 = 0.f;
#pragma unroll
            for (int i = 0; i < 4; i++) {
                int idx = i * 64 + lane;
                float4 h4 = hv[idx];
                a3 += dot4(((const float4*)(w_hh + (size_t)j * H))[idx], h4);
                a4 += dot4(((const float4*)(w_hh + (size_t)(H + j) * H))[idx], h4);
                a5 += dot4(((const float4*)(w_hh + (size_t)(2 * H + j) * H))[idx], h4);
            }
            a3 = wave_reduce(a3); a4 = wave_reduce(a4); a5 = wave_reduce(a5);
            if (lane == 0) {
                gh[j] = a3 + b_hh[j];
                gh[H + j] = a4 + b_hh[H + j];
                gh[2 * H + j] = a5 + b_hh[2 * H + j];
            }
        }
    }
    grid_sync(bar);

    // ---------------- stage 1: scores GEMM (128x128 tile/block) ----------
    {
        const int bx = blk & 31, by = blk >> 5;          // 32 x 8
        const int r0b = bx * 128, jc0b = by * 128;
        const int wm = wid >> 1, wn = wid & 1;            // 4 x 2 waves
        const int mrow = lane & 15, quad = lane >> 4;

        f32x4 acc[2][4];
#pragma unroll
        for (int mt = 0; mt < 2; mt++)
#pragma unroll
            for (int jt = 0; jt < 4; jt++) acc[mt][jt] = (f32x4){0.f, 0.f, 0.f, 0.f};

        for (int k0 = 0; k0 < H; k0 += 64) {
            // A: 128 rows x 64 k = 1024 x 16B chunks, 2 per thread
#pragma unroll
            for (int c = 0; c < 2; c++) {
                int chunk = c * NTHR + tid;
                int row = chunk >> 3, ko = (chunk & 7) * 8;
                *(uint4*)(Als + row * APITCH + ko) =
                    *(const uint4*)(enc_bf + (size_t)(r0b + row) * H + k0 + ko);
            }
            // B: 128 j x 64 k, 2 per thread
#pragma unroll
            for (int c = 0; c < 2; c++) {
                int chunk = c * NTHR + tid;
                int j = chunk >> 3, ko = (chunk & 7) * 8;
                *(uint4*)(Bls + j * APITCH + ko) =
                    *(const uint4*)(u_bf + (size_t)(jc0b + j) * H + k0 + ko);
            }
            __syncthreads();

            bf16x8 a[2][2];
#pragma unroll
            for (int mt = 0; mt < 2; mt++) {
                const unsigned short* abase =
                    Als + (wm * 32 + mt * 16 + mrow) * APITCH + quad * 8;
                a[mt][0] = *(const bf16x8*)(abase);
                a[mt][1] = *(const bf16x8*)(abase + 32);
            }
#pragma unroll
            for (int jt = 0; jt < 4; jt++) {
                const unsigned short* bbase =
                    Bls + (wn * 64 + jt * 16 + mrow) * APITCH + quad * 8;
                bf16x8 b0 = *(const bf16x8*)(bbase);
                bf16x8 b1 = *(const bf16x8*)(bbase + 32);
#pragma unroll
                for (int mt = 0; mt < 2; mt++) {
                    acc[mt][jt] = __builtin_amdgcn_mfma_f32_16x16x32_bf16(a[mt][0], b0, acc[mt][jt], 0, 0, 0);
                    acc[mt][jt] = __builtin_amdgcn_mfma_f32_16x16x32_bf16(a[mt][1], b1, acc[mt][jt], 0, 0, 0);
                }
            }
            __syncthreads();
        }

        // epilogue: per row sum vj * tanh(S + wh[j]) over this block's 128 j
        float sacc[2][4] = {{0.f, 0.f, 0.f, 0.f}, {0.f, 0.f, 0.f, 0.f}};
#pragma unroll
        for (int jt = 0; jt < 4; jt++) {
            int jcol = jc0b + wn * 64 + jt * 16 + mrow;
            float vj = vW[jcol];
            float whv = wh[jcol];
#pragma unroll
            for (int mt = 0; mt < 2; mt++)
#pragma unroll
                for (int r = 0; r < 4; r++)
                    sacc[mt][r] += vj * tanhf(acc[mt][jt][r] + whv);
        }
#pragma unroll
        for (int mt = 0; mt < 2; mt++)
#pragma unroll
            for (int r = 0; r < 4; r++) {
                float s = sacc[mt][r];
                s += __shfl_xor(s, 1);
                s += __shfl_xor(s, 2);
                s += __shfl_xor(s, 4);
                s += __shfl_xor(s, 8);
                if (mrow == 0)
                    atomicAdd(&scores[r0b + wm * 32 + mt * 16 + quad * 4 + r], s);
            }
    }
    grid_sync(bar);

    // ---------------- stage 2: softmax + context + attn_out --------------
    {
        const int cx = blk & 1, ly = blk >> 1;            // 2 col x 128 l
        float4 s0 = ((const float4*)scores)[tid];
        float4 s1 = ((const float4*)scores)[512 + tid];
        float m = fmaxf(fmaxf(fmaxf(s0.x, s0.y), fmaxf(s0.z, s0.w)),
                        fmaxf(fmaxf(s1.x, s1.y), fmaxf(s1.z, s1.w)));
        for (int off = 32; off; off >>= 1) m = fmaxf(m, __shfl_xor(m, off));
        if (lane == 0) smax[wid] = m;
        __syncthreads();
        float gmax = smax[0];
#pragma unroll
        for (int w = 1; w < 8; w++) gmax = fmaxf(gmax, smax[w]);
        float e = expf(s0.x - gmax) + expf(s0.y - gmax) + expf(s0.z - gmax) + expf(s0.w - gmax)
                + expf(s1.x - gmax) + expf(s1.y - gmax) + expf(s1.z - gmax) + expf(s1.w - gmax);
        e = wave_reduce(e);
        if (lane == 0) ssum[wid] = e;
        __syncthreads();
        float tot = ssum[0];
#pragma unroll
        for (int w = 1; w < 8; w++) tot += ssum[w];
        float inv = 1.0f / tot;

        int l0 = ly * 32;
        if (tid < 32) attn_l[tid] = expf(scores[l0 + tid] - gmax) * inv;
        __syncthreads();

        if (blk == 0) {
            float* attn_out = out + V + H;
            float4 a0 = make_float4(expf(s0.x - gmax) * inv, expf(s0.y - gmax) * inv,
                                    expf(s0.z - gmax) * inv, expf(s0.w - gmax) * inv);
            float4 a1 = make_float4(expf(s1.x - gmax) * inv, expf(s1.y - gmax) * inv,
                                    expf(s1.z - gmax) * inv, expf(s1.w - gmax) * inv);
            ((float4*)attn_out)[tid] = a0;
            ((float4*)attn_out)[512 + tid] = a1;
        }

        int col = cx * 512 + tid;
        float acc = 0.f;
#pragma unroll 4
        for (int l = 0; l < 32; l++)
            acc += attn_l[l] * bf16_to_f32(enc_bf[(size_t)(l0 + l) * H + col]);
        atomicAdd(&context[col], acc);
    }
    grid_sync(bar);

    // ---------------- stage 3: combine (x = relu([ctx; emb] @ cW.T + cb)) -
    {
        if (gw < H) {
            int t0 = token[0];
            const float4* row = (const float4*)(cW + (size_t)gw * 2 * H);
            const float4* cv = (const float4*)context;
            const float4* ev = (const float4*)(emb + (size_t)t0 * H);
            float acc = 0.f;
#pragma unroll
            for (int i = 0; i < 4; i++) {
                int idx = i * 64 + lane;
                acc += dot4(row[idx], cv[idx]);
                acc += dot4(row[256 + idx], ev[idx]);
            }
            acc = wave_reduce(acc);
            if (lane == 0) xvec[gw] = fmaxf(acc + cb[gw], 0.f);
        }
    }
    grid_sync(bar);

    // ---------------- stage 4: GRU cell (gi GEMV; gh precomputed) --------
    {
        if (gw < H) {
            int j = gw;
            const float4* xv = (const float4*)xvec;
            float a0 = 0.f, a1 = 0.f, a2 = 0.f;
#pragma unroll
            for (int i = 0; i < 4; i++) {
                int idx = i * 64 + lane;
                float4 x4 = xv[idx];
                a0 += dot4(((const float4*)(w_ih + (size_t)j * H))[idx], x4);
                a1 += dot4(((const float4*)(w_ih + (size_t)(H + j) * H))[idx], x4);
                a2 += dot4(((const float4*)(w_ih + (size_t)(2 * H + j) * H))[idx], x4);
            }
            a0 = wave_reduce(a0); a1 = wave_reduce(a1); a2 = wave_reduce(a2);
            if (lane == 0) {
                float ir = a0 + b_ih[j], iz = a1 + b_ih[H + j], inn = a2 + b_ih[2 * H + j];
                float r = 1.f / (1.f + expf(-(ir + gh[j])));
                float z = 1.f / (1.f + expf(-(iz + gh[H + j])));
                float n = tanhf(inn + r * gh[2 * H + j]);
                float hp = hidden[j];
                float hval = (1.f - z) * n + z * hp;
                out[V + j] = hval;                    // new hidden
                ovec[j] = context[j] + hval;          // residual for logits
            }
        }
    }
    grid_sync(bar);

    // ---------------- stage 5: logits GEMV (16 rows per wave) ------------
    {
        const float4* ov = (const float4*)ovec;
        float4 o4[4];
#pragma unroll
        for (int t = 0; t < 4; t++) o4[t] = ov[t * 64 + lane];
        int base = gw * 16;
        for (int p = 0; p < 8; p++) {
            int i0 = base + p * 2;
            if (i0 >= V) break;
            const float4* row0 = (const float4*)(outW + (size_t)i0 * H);
            const float4* row1 = row0 + 256;
            float acc0 = 0.f, acc1 = 0.f;
#pragma unroll
            for (int t = 0; t < 4; t++) {
                int idx = t * 64 + lane;
                acc0 += dot4(row0[idx], o4[t]);
                acc1 += dot4(row1[idx], o4[t]);
            }
            acc0 = wave_reduce(acc0);
            acc1 = wave_reduce(acc1);
            if (lane == 0) {
                out[i0] = acc0 + outb[i0];
                out[i0 + 1] = acc1 + outb[i0 + 1];
            }
        }
    }
}

extern "C" void kernel_launch(void* const* d_in, const int* in_sizes, int n_in,
                              void* d_out, int out_size, void* d_ws, size_t ws_size,
                              hipStream_t stream) {
    const int* token = (const int*)d_in[0];
    const float* hidden = (const float*)d_in[1];   // (1,1,H) == hprev == h0
    const float* enc = (const float*)d_in[2];
    const float* emb = (const float*)d_in[3];
    const float* wW = (const float*)d_in[4];
    const float* wb = (const float*)d_in[5];
    const float* uW = (const float*)d_in[6];
    const float* ub = (const float*)d_in[7];
    const float* vW = (const float*)d_in[8];
    const float* cW = (const float*)d_in[9];
    const float* cb = (const float*)d_in[10];
    const float* w_ih = (const float*)d_in[11];
    const float* b_ih = (const float*)d_in[12];
    const float* w_hh = (const float*)d_in[13];
    const float* b_hh = (const float*)d_in[14];
    const float* outW = (const float*)d_in[15];
    const float* outb = (const float*)d_in[16];
    float* out = (float*)d_out;

    char* ws = (char*)d_ws;
    unsigned* bar = (unsigned*)ws;                 // 2 x u32 barrier state
    float* wh = (float*)(ws + 4096);               // H
    float* gh = wh + H;                            // 3H
    float* scores = gh + 3 * H;                    // L
    float* context = scores + L;                   // H
    float* xvec = context + H;                     // H
    float* ovec = xvec + H;                        // H
    unsigned short* enc_bf = (unsigned short*)(ws + (1 << 20));  // 8 MiB
    unsigned short* u_bf = enc_bf + (size_t)L * H;               // 2 MiB

    // Arrival counter must start at 0 (ws is poisoned between iterations).
    hipMemsetAsync(ws, 0, 8, stream);
    mega_kernel<<<NBLK, NTHR, 0, stream>>>(token, hidden, enc, emb, wW, wb, uW, ub,
                                           vW, cW, cb, w_ih, b_ih, w_hh, b_hh,
                                           outW, outb, out,
                                           bar, wh, gh, scores, context, xvec, ovec,
                                           enc_bf, u_bf);
}

// Round 4
// 384.765 us; speedup vs baseline: 2.2079x; 2.2079x over previous
//
#include <hip/hip_runtime.h>
#include <math.h>

#define H 1024
#define V 32000
#define L 4096
#define APITCH 72

typedef __bf16 bf16x8 __attribute__((ext_vector_type(8)));
typedef float f32x4 __attribute__((ext_vector_type(4)));

__device__ __forceinline__ unsigned short f32_to_bf16(float f) {
    unsigned int u = __float_as_uint(f);
    unsigned int r = (u + 0x7fffu + ((u >> 16) & 1u)) >> 16;
    return (unsigned short)r;
}

__device__ __forceinline__ uint4 pack_bf16_8(float4 a, float4 b) {
    uint4 r;
    r.x = (unsigned)f32_to_bf16(a.x) | ((unsigned)f32_to_bf16(a.y) << 16);
    r.y = (unsigned)f32_to_bf16(a.z) | ((unsigned)f32_to_bf16(a.w) << 16);
    r.z = (unsigned)f32_to_bf16(b.x) | ((unsigned)f32_to_bf16(b.y) << 16);
    r.w = (unsigned)f32_to_bf16(b.z) | ((unsigned)f32_to_bf16(b.w) << 16);
    return r;
}

__device__ __forceinline__ float dot4(float4 a, float4 b) {
    return a.x * b.x + a.y * b.y + a.z * b.z + a.w * b.w;
}

__device__ __forceinline__ float wave_reduce(float v) {
    for (int off = 32; off; off >>= 1) v += __shfl_xor(v, off);
    return v;
}

// K1: fused scores GEMM. 128x128 tile per block, grid (32, 8) x 512 threads.
// - prologue: each block computes wh[jc0..+128) redundantly (wW L2/L3-hot)
// - staging: converts enc/uW f32 -> bf16 on the fly (no prep kernel,
//   no enc_bf/u_bf workspace round-trip)
// - epilogue: scores[l] += sum_j vW[j] * tanh(S[l][j] + wh[j]) via atomicAdd
// scores must be pre-zeroed (hipMemsetAsync graph node).
__global__ __launch_bounds__(512) void scores_kernel(
        const float* __restrict__ enc,
        const float* __restrict__ uW,
        const float* __restrict__ wW,
        const float* __restrict__ wb,
        const float* __restrict__ ub,
        const float* __restrict__ hidden,
        const float* __restrict__ vW,
        float* __restrict__ scores) {
    __shared__ unsigned short Als[128 * APITCH];
    __shared__ unsigned short Bls[128 * APITCH];
    __shared__ float wh_s[128];

    const int tid = threadIdx.x;
    const int bx = blockIdx.x, by = blockIdx.y;
    const int r0b = bx * 128, jc0b = by * 128;
    const int wid = tid >> 6, lane = tid & 63;

    // ---- prologue: wh_s[jl] = wW[jc0b+jl,:].h0 + wb + ub  (4 lanes per jl)
    {
        int jl = tid >> 2, part = tid & 3;
        const float4* row = (const float4*)(wW + (size_t)(jc0b + jl) * H);
        const float4* hv = (const float4*)hidden;
        float acc = 0.f;
#pragma unroll 8
        for (int i = 0; i < 64; i++) {
            int idx = part * 64 + i;
            acc += dot4(row[idx], hv[idx]);
        }
        acc += __shfl_xor(acc, 1);
        acc += __shfl_xor(acc, 2);
        if (part == 0) wh_s[jl] = acc + wb[jc0b + jl] + ub[jc0b + jl];
    }
    // visibility of wh_s covered by the K-loop's __syncthreads (first
    // consumer is the epilogue, far after).

    const int wm = wid >> 1, wn = wid & 1;          // 4x2 waves
    const int mrow = lane & 15, quad = lane >> 4;
    const int srow = tid >> 2, seg = tid & 3;       // staging: row/j + 16k seg

    f32x4 acc[2][4];
#pragma unroll
    for (int mt = 0; mt < 2; mt++)
#pragma unroll
        for (int jt = 0; jt < 4; jt++) acc[mt][jt] = (f32x4){0.f, 0.f, 0.f, 0.f};

    for (int k0 = 0; k0 < H; k0 += 64) {
        // stage A: enc rows (f32 -> bf16), 16 floats per thread
        {
            const float4* src = (const float4*)(enc + (size_t)(r0b + srow) * H + k0 + seg * 16);
            float4 f0 = src[0], f1 = src[1], f2 = src[2], f3 = src[3];
            unsigned short* dst = Als + srow * APITCH + seg * 16;
            *(uint4*)(dst) = pack_bf16_8(f0, f1);
            *(uint4*)(dst + 8) = pack_bf16_8(f2, f3);
        }
        // stage B: uW rows (f32 -> bf16)
        {
            const float4* src = (const float4*)(uW + (size_t)(jc0b + srow) * H + k0 + seg * 16);
            float4 g0 = src[0], g1 = src[1], g2 = src[2], g3 = src[3];
            unsigned short* dst = Bls + srow * APITCH + seg * 16;
            *(uint4*)(dst) = pack_bf16_8(g0, g1);
            *(uint4*)(dst + 8) = pack_bf16_8(g2, g3);
        }
        __syncthreads();

        bf16x8 a[2][2];
#pragma unroll
        for (int mt = 0; mt < 2; mt++) {
            const unsigned short* abase =
                Als + (wm * 32 + mt * 16 + mrow) * APITCH + quad * 8;
            a[mt][0] = *(const bf16x8*)(abase);
            a[mt][1] = *(const bf16x8*)(abase + 32);
        }
#pragma unroll
        for (int jt = 0; jt < 4; jt++) {
            const unsigned short* bbase =
                Bls + (wn * 64 + jt * 16 + mrow) * APITCH + quad * 8;
            bf16x8 b0 = *(const bf16x8*)(bbase);
            bf16x8 b1 = *(const bf16x8*)(bbase + 32);
#pragma unroll
            for (int mt = 0; mt < 2; mt++) {
                acc[mt][jt] = __builtin_amdgcn_mfma_f32_16x16x32_bf16(a[mt][0], b0, acc[mt][jt], 0, 0, 0);
                acc[mt][jt] = __builtin_amdgcn_mfma_f32_16x16x32_bf16(a[mt][1], b1, acc[mt][jt], 0, 0, 0);
            }
        }
        __syncthreads();
    }

    // epilogue: per row sum vj * tanh(S + wh[j]) over this block's 128 j
    float sacc[2][4] = {{0.f, 0.f, 0.f, 0.f}, {0.f, 0.f, 0.f, 0.f}};
#pragma unroll
    for (int jt = 0; jt < 4; jt++) {
        int jl = wn * 64 + jt * 16 + mrow;
        float vj = vW[jc0b + jl];
        float whv = wh_s[jl];
#pragma unroll
        for (int mt = 0; mt < 2; mt++)
#pragma unroll
            for (int r = 0; r < 4; r++)
                sacc[mt][r] += vj * tanhf(acc[mt][jt][r] + whv);
    }
#pragma unroll
    for (int mt = 0; mt < 2; mt++)
#pragma unroll
        for (int r = 0; r < 4; r++) {
            float s = sacc[mt][r];
            s += __shfl_xor(s, 1);
            s += __shfl_xor(s, 2);
            s += __shfl_xor(s, 4);
            s += __shfl_xor(s, 8);
            if (mrow == 0)
                atomicAdd(&scores[r0b + wm * 32 + mt * 16 + quad * 4 + r], s);
        }
}

// K2: fused softmax + context. Grid (4 col-chunks, 128 l-chunks) x 256.
// Every block recomputes softmax stats from scores[L] (16 KB, L2-hot),
// then accumulates its 32-l x 256-col partial of context via atomicAdd,
// reading enc in f32. Block (0,0) also writes the attn_weights output.
__global__ __launch_bounds__(256) void ctx_softmax_kernel(
        const float* __restrict__ scores,
        const float* __restrict__ enc,
        float* __restrict__ context,
        float* __restrict__ attn_out) {
    __shared__ float smax[4];
    __shared__ float ssum[4];
    __shared__ float attn_l[32];
    int tid = threadIdx.x;
    int wid = tid >> 6, lane = tid & 63;
    float4 s0 = ((const float4*)scores)[tid];
    float4 s1 = ((const float4*)scores)[256 + tid];
    float4 s2 = ((const float4*)scores)[512 + tid];
    float4 s3 = ((const float4*)scores)[768 + tid];
    float m = fmaxf(fmaxf(fmaxf(s0.x, s0.y), fmaxf(s0.z, s0.w)),
                    fmaxf(fmaxf(s1.x, s1.y), fmaxf(s1.z, s1.w)));
    m = fmaxf(m, fmaxf(fmaxf(s2.x, s2.y), fmaxf(s2.z, s2.w)));
    m = fmaxf(m, fmaxf(fmaxf(s3.x, s3.y), fmaxf(s3.z, s3.w)));
    for (int off = 32; off; off >>= 1) m = fmaxf(m, __shfl_xor(m, off));
    if (lane == 0) smax[wid] = m;
    __syncthreads();
    float gmax = fmaxf(fmaxf(smax[0], smax[1]), fmaxf(smax[2], smax[3]));
    float e = expf(s0.x - gmax) + expf(s0.y - gmax) + expf(s0.z - gmax) + expf(s0.w - gmax)
            + expf(s1.x - gmax) + expf(s1.y - gmax) + expf(s1.z - gmax) + expf(s1.w - gmax)
            + expf(s2.x - gmax) + expf(s2.y - gmax) + expf(s2.z - gmax) + expf(s2.w - gmax)
            + expf(s3.x - gmax) + expf(s3.y - gmax) + expf(s3.z - gmax) + expf(s3.w - gmax);
    e = wave_reduce(e);
    if (lane == 0) ssum[wid] = e;
    __syncthreads();
    float inv = 1.0f / (ssum[0] + ssum[1] + ssum[2] + ssum[3]);

    int l0 = blockIdx.y * 32;
    if (tid < 32) attn_l[tid] = expf(scores[l0 + tid] - gmax) * inv;
    __syncthreads();

    if (blockIdx.x == 0 && blockIdx.y == 0) {
        float4 a0 = make_float4(expf(s0.x - gmax) * inv, expf(s0.y - gmax) * inv,
                                expf(s0.z - gmax) * inv, expf(s0.w - gmax) * inv);
        float4 a1 = make_float4(expf(s1.x - gmax) * inv, expf(s1.y - gmax) * inv,
                                expf(s1.z - gmax) * inv, expf(s1.w - gmax) * inv);
        float4 a2 = make_float4(expf(s2.x - gmax) * inv, expf(s2.y - gmax) * inv,
                                expf(s2.z - gmax) * inv, expf(s2.w - gmax) * inv);
        float4 a3 = make_float4(expf(s3.x - gmax) * inv, expf(s3.y - gmax) * inv,
                                expf(s3.z - gmax) * inv, expf(s3.w - gmax) * inv);
        ((float4*)attn_out)[tid] = a0;
        ((float4*)attn_out)[256 + tid] = a1;
        ((float4*)attn_out)[512 + tid] = a2;
        ((float4*)attn_out)[768 + tid] = a3;
    }

    int col = blockIdx.x * 256 + tid;
    float acc = 0.f;
#pragma unroll 4
    for (int l = 0; l < 32; l++)
        acc += attn_l[l] * enc[(size_t)(l0 + l) * H + col];
    atomicAdd(&context[col], acc);
}

// K3: x[j] = relu([context; emb[token]] . cW[j,:] + cb[j]), one wave per j.
__global__ void combine_kernel(const float* __restrict__ context,
                               const int* __restrict__ token,
                               const float* __restrict__ emb,
                               const float* __restrict__ cW,
                               const float* __restrict__ cb,
                               float* __restrict__ xvec) {
    int wave = (blockIdx.x * blockDim.x + threadIdx.x) >> 6;
    int lane = threadIdx.x & 63;
    if (wave >= H) return;
    const float4* row = (const float4*)(cW + (size_t)wave * 2 * H);
    const float4* cv = (const float4*)context;
    const float4* ev = (const float4*)(emb + (size_t)token[0] * H);
    float acc = 0.f;
#pragma unroll
    for (int i = 0; i < 4; i++) {
        int idx = i * 64 + lane;
        acc += dot4(row[idx], cv[idx]);
        acc += dot4(row[256 + idx], ev[idx]);
    }
    acc = wave_reduce(acc);
    if (lane == 0) xvec[wave] = fmaxf(acc + cb[wave], 0.f);
}

// K4: GRU cell, one wave per hidden unit j (6 dot products of K=1024).
__global__ void gru_kernel(const float* __restrict__ xvec,
                           const float* __restrict__ hprev,
                           const float* __restrict__ w_ih,
                           const float* __restrict__ b_ih,
                           const float* __restrict__ w_hh,
                           const float* __restrict__ b_hh,
                           const float* __restrict__ context,
                           float* __restrict__ hnew_out,   // out + V
                           float* __restrict__ ovec) {
    int j = (blockIdx.x * blockDim.x + threadIdx.x) >> 6;
    int lane = threadIdx.x & 63;
    if (j >= H) return;
    const float4* xv = (const float4*)xvec;
    const float4* hv = (const float4*)hprev;
    float a0 = 0.f, a1 = 0.f, a2 = 0.f, a3 = 0.f, a4 = 0.f, a5 = 0.f;
#pragma unroll
    for (int i = 0; i < 4; i++) {
        int idx = i * 64 + lane;
        float4 x4 = xv[idx], h4 = hv[idx];
        a0 += dot4(((const float4*)(w_ih + (size_t)j * H))[idx], x4);
        a1 += dot4(((const float4*)(w_ih + (size_t)(H + j) * H))[idx], x4);
        a2 += dot4(((const float4*)(w_ih + (size_t)(2 * H + j) * H))[idx], x4);
        a3 += dot4(((const float4*)(w_hh + (size_t)j * H))[idx], h4);
        a4 += dot4(((const float4*)(w_hh + (size_t)(H + j) * H))[idx], h4);
        a5 += dot4(((const float4*)(w_hh + (size_t)(2 * H + j) * H))[idx], h4);
    }
    a0 = wave_reduce(a0); a1 = wave_reduce(a1); a2 = wave_reduce(a2);
    a3 = wave_reduce(a3); a4 = wave_reduce(a4); a5 = wave_reduce(a5);
    if (lane == 0) {
        float ir = a0 + b_ih[j], iz = a1 + b_ih[H + j], inn = a2 + b_ih[2 * H + j];
        float hr = a3 + b_hh[j], hz = a4 + b_hh[H + j], hn = a5 + b_hh[2 * H + j];
        float r = 1.f / (1.f + expf(-(ir + hr)));
        float z = 1.f / (1.f + expf(-(iz + hz)));
        float n = tanhf(inn + r * hn);
        float hp = hprev[j];
        float hval = (1.f - z) * n + z * hp;
        hnew_out[j] = hval;
        ovec[j] = context[j] + hval;
    }
}

// K5: logits GEMV, 2 rows per wave (8 in-flight 16B loads per lane).
__global__ __launch_bounds__(256) void logits_kernel(
        const float* __restrict__ ovec,
        const float* __restrict__ outW,
        const float* __restrict__ outb,
        float* __restrict__ out) {
    int wave = (blockIdx.x * blockDim.x + threadIdx.x) >> 6;
    int lane = threadIdx.x & 63;
    int i0 = wave * 2;
    if (i0 >= V) return;
    const float4* row0 = (const float4*)(outW + (size_t)i0 * H);
    const float4* row1 = (const float4*)(outW + (size_t)(i0 + 1) * H);
    const float4* ov = (const float4*)ovec;
    float acc0 = 0.f, acc1 = 0.f;
#pragma unroll
    for (int t = 0; t < 4; t++) {
        int idx = t * 64 + lane;
        float4 o4 = ov[idx];
        acc0 += dot4(row0[idx], o4);
        acc1 += dot4(row1[idx], o4);
    }
    acc0 = wave_reduce(acc0);
    acc1 = wave_reduce(acc1);
    if (lane == 0) {
        out[i0] = acc0 + outb[i0];
        out[i0 + 1] = acc1 + outb[i0 + 1];
    }
}

extern "C" void kernel_launch(void* const* d_in, const int* in_sizes, int n_in,
                              void* d_out, int out_size, void* d_ws, size_t ws_size,
                              hipStream_t stream) {
    const int* token = (const int*)d_in[0];
    const float* hidden = (const float*)d_in[1];   // (1,1,H) == hprev == h0
    const float* enc = (const float*)d_in[2];
    const float* emb = (const float*)d_in[3];
    const float* wW = (const float*)d_in[4];
    const float* wb = (const float*)d_in[5];
    const float* uW = (const float*)d_in[6];
    const float* ub = (const float*)d_in[7];
    const float* vW = (const float*)d_in[8];
    const float* cW = (const float*)d_in[9];
    const float* cb = (const float*)d_in[10];
    const float* w_ih = (const float*)d_in[11];
    const float* b_ih = (const float*)d_in[12];
    const float* w_hh = (const float*)d_in[13];
    const float* b_hh = (const float*)d_in[14];
    const float* outW = (const float*)d_in[15];
    const float* outb = (const float*)d_in[16];
    float* out = (float*)d_out;

    char* ws = (char*)d_ws;
    float* scores = (float*)ws;              // L  (atomicAdd target)
    float* context = scores + L;             // H  (atomicAdd target)
    float* xvec = context + H;               // H
    float* ovec = xvec + H;                  // H

    // zero the two accumulation buffers (cheap graph memset node)
    hipMemsetAsync(ws, 0, (size_t)(L + H) * sizeof(float), stream);

    scores_kernel<<<dim3(32, 8), 512, 0, stream>>>(enc, uW, wW, wb, ub, hidden,
                                                   vW, scores);
    ctx_softmax_kernel<<<dim3(4, 128), 256, 0, stream>>>(scores, enc, context,
                                                         out + V + H);
    combine_kernel<<<256, 256, 0, stream>>>(context, token, emb, cW, cb, xvec);
    gru_kernel<<<256, 256, 0, stream>>>(xvec, hidden, w_ih, b_ih, w_hh, b_hh,
                                        context, out + V, ovec);
    logits_kernel<<<4000, 256, 0, stream>>>(ovec, outW, outb, out);
}

// Round 5
// 338.162 us; speedup vs baseline: 2.5122x; 1.1378x over previous
//
#include <hip/hip_runtime.h>
#include <hip/hip_bf16.h>
#include <math.h>

#define H 1024
#define V 32000
#define L 4096

typedef __bf16 bf16x8 __attribute__((ext_vector_type(8)));
typedef float f32x4 __attribute__((ext_vector_type(4)));

__device__ __forceinline__ unsigned short f32_to_bf16(float f) {
    unsigned int u = __float_as_uint(f);
    unsigned int r = (u + 0x7fffu + ((u >> 16) & 1u)) >> 16;
    return (unsigned short)r;
}

__device__ __forceinline__ float bf16_to_f32(unsigned short s) {
    return __uint_as_float(((unsigned int)s) << 16);
}

__device__ __forceinline__ float dot4(float4 a, float4 b) {
    return a.x * b.x + a.y * b.y + a.z * b.z + a.w * b.w;
}

__device__ __forceinline__ float wave_reduce(float v) {
    for (int off = 32; off; off >>= 1) v += __shfl_xor(v, off);
    return v;
}

// K1: fused prep (f32->bf16 of enc, uW) + wh GEMV + gh GEMV (GRU hprev
// gates, hoisted here since they depend only on inputs) + scores zeroing.
// Blocks 0..1023: conversion (grid-stride). Blocks 1024..1279: GEMVs
// (1024 waves, one hidden unit j per wave: 4 dot products of K=1024).
__global__ __launch_bounds__(256) void prep_kernel(
        const float* __restrict__ enc,
        const float* __restrict__ uW,
        const float* __restrict__ h0,
        const float* __restrict__ wW,
        const float* __restrict__ wb,
        const float* __restrict__ ub,
        const float* __restrict__ w_hh,
        const float* __restrict__ b_hh,
        unsigned short* __restrict__ enc_bf,
        unsigned short* __restrict__ u_bf,
        float* __restrict__ wh,
        float* __restrict__ gh,      // 3H: r,z,n gate pre-acts from hprev
        float* __restrict__ scores) {
    if (blockIdx.x < 1024) {
        int tid = blockIdx.x * 256 + threadIdx.x;
        const int stride = 1024 * 256;
        const int NE = L * H / 4;
        const int NU = H * H / 4;
        for (int i = tid; i < NE; i += stride) {
            float4 f = ((const float4*)enc)[i];
            ushort4 o;
            o.x = f32_to_bf16(f.x); o.y = f32_to_bf16(f.y);
            o.z = f32_to_bf16(f.z); o.w = f32_to_bf16(f.w);
            ((ushort4*)enc_bf)[i] = o;
        }
        for (int i = tid; i < NU; i += stride) {
            float4 f = ((const float4*)uW)[i];
            ushort4 o;
            o.x = f32_to_bf16(f.x); o.y = f32_to_bf16(f.y);
            o.z = f32_to_bf16(f.z); o.w = f32_to_bf16(f.w);
            ((ushort4*)u_bf)[i] = o;
        }
    } else {
        // zero scores (atomicAdd target): first 16 of these 256 blocks
        int z = (blockIdx.x - 1024) * 256 + threadIdx.x;
        if (z < L) scores[z] = 0.f;
        int j = ((blockIdx.x - 1024) * 256 + threadIdx.x) >> 6;   // 0..1023
        int lane = threadIdx.x & 63;
        const float4* rw = (const float4*)(wW + (size_t)j * H);
        const float4* r3 = (const float4*)(w_hh + (size_t)j * H);
        const float4* r4 = (const float4*)(w_hh + (size_t)(H + j) * H);
        const float4* r5 = (const float4*)(w_hh + (size_t)(2 * H + j) * H);
        const float4* hv = (const float4*)h0;
        float aw = 0.f, a3 = 0.f, a4 = 0.f, a5 = 0.f;
#pragma unroll
        for (int i = 0; i < 4; i++) {
            int idx = i * 64 + lane;
            float4 h4 = hv[idx];
            aw += dot4(rw[idx], h4);
            a3 += dot4(r3[idx], h4);
            a4 += dot4(r4[idx], h4);
            a5 += dot4(r5[idx], h4);
        }
        aw = wave_reduce(aw);
        a3 = wave_reduce(a3); a4 = wave_reduce(a4); a5 = wave_reduce(a5);
        if (lane == 0) {
            wh[j] = aw + wb[j] + ub[j];
            gh[j] = a3 + b_hh[j];
            gh[H + j] = a4 + b_hh[H + j];
            gh[2 * H + j] = a5 + b_hh[2 * H + j];
        }
    }
}

// K2: LDS-tiled fused scores GEMM, M=64 x N=128 per block.
// Grid (64, 8) = 512 blocks (2/CU). 4 waves in 2x2; each wave 32 rows x 64 j.
// Partial tanh-weighted sums accumulate into scores[L] via atomicAdd.
// Block (0,0) also zeroes context for the next kernel's atomicAdds.
#define APITCH 72
__global__ __launch_bounds__(256) void scores_kernel(
        const unsigned short* __restrict__ enc_bf,
        const unsigned short* __restrict__ u_bf,
        const float* __restrict__ wh,
        const float* __restrict__ vW,
        float* __restrict__ scores,
        float* __restrict__ context) {
    __shared__ unsigned short Als[64 * APITCH];
    __shared__ unsigned short Bls[128 * APITCH];
    int tid = threadIdx.x;
    if (blockIdx.x == 0 && blockIdx.y == 0) {
        ((float4*)context)[tid] = make_float4(0.f, 0.f, 0.f, 0.f);  // 1024 floats
    }
    int wave = tid >> 6, lane = tid & 63;
    int wm = wave >> 1, wn = wave & 1;
    int mrow = lane & 15, quad = lane >> 4;
    int r0b = blockIdx.x * 64;
    int jc0b = blockIdx.y * 128;

    f32x4 acc[2][4];
#pragma unroll
    for (int mt = 0; mt < 2; mt++)
#pragma unroll
        for (int jt = 0; jt < 4; jt++) acc[mt][jt] = (f32x4){0.f, 0.f, 0.f, 0.f};

    for (int k0 = 0; k0 < H; k0 += 64) {
        // Stage A: 64 rows x 64 k = 512 x 16B chunks, 2 per thread.
#pragma unroll
        for (int c = 0; c < 2; c++) {
            int chunk = c * 256 + tid;
            int row = chunk >> 3, ko = (chunk & 7) * 8;
            *(uint4*)(Als + row * APITCH + ko) =
                *(const uint4*)(enc_bf + (size_t)(r0b + row) * H + k0 + ko);
        }
        // Stage B: 128 j x 64 k = 1024 x 16B chunks, 4 per thread.
#pragma unroll
        for (int c = 0; c < 4; c++) {
            int chunk = c * 256 + tid;
            int j = chunk >> 3, ko = (chunk & 7) * 8;
            *(uint4*)(Bls + j * APITCH + ko) =
                *(const uint4*)(u_bf + (size_t)(jc0b + j) * H + k0 + ko);
        }
        __syncthreads();

        bf16x8 a[2][2];
#pragma unroll
        for (int mt = 0; mt < 2; mt++) {
            const unsigned short* abase =
                Als + (wm * 32 + mt * 16 + mrow) * APITCH + quad * 8;
            a[mt][0] = *(const bf16x8*)(abase);
            a[mt][1] = *(const bf16x8*)(abase + 32);
        }
#pragma unroll
        for (int jt = 0; jt < 4; jt++) {
            const unsigned short* bbase =
                Bls + (wn * 64 + jt * 16 + mrow) * APITCH + quad * 8;
            bf16x8 b0 = *(const bf16x8*)(bbase);
            bf16x8 b1 = *(const bf16x8*)(bbase + 32);
#pragma unroll
            for (int mt = 0; mt < 2; mt++) {
                acc[mt][jt] = __builtin_amdgcn_mfma_f32_16x16x32_bf16(a[mt][0], b0, acc[mt][jt], 0, 0, 0);
                acc[mt][jt] = __builtin_amdgcn_mfma_f32_16x16x32_bf16(a[mt][1], b1, acc[mt][jt], 0, 0, 0);
            }
        }
        __syncthreads();
    }

    // Epilogue: per row, sum vj*tanh(S+wh) over this block's 64 j.
    // C/D layout: col = lane&15 (j), row = quad*4 + r.
    float sacc[2][4] = {{0.f, 0.f, 0.f, 0.f}, {0.f, 0.f, 0.f, 0.f}};
#pragma unroll
    for (int jt = 0; jt < 4; jt++) {
        int jcol = jc0b + wn * 64 + jt * 16 + mrow;
        float vj = vW[jcol];
        float whv = wh[jcol];
#pragma unroll
        for (int mt = 0; mt < 2; mt++)
#pragma unroll
            for (int r = 0; r < 4; r++)
                sacc[mt][r] += vj * tanhf(acc[mt][jt][r] + whv);
    }
#pragma unroll
    for (int mt = 0; mt < 2; mt++)
#pragma unroll
        for (int r = 0; r < 4; r++) {
            float s = sacc[mt][r];
            s += __shfl_xor(s, 1);
            s += __shfl_xor(s, 2);
            s += __shfl_xor(s, 4);
            s += __shfl_xor(s, 8);
            if (mrow == 0)
                atomicAdd(&scores[r0b + wm * 32 + mt * 16 + quad * 4 + r], s);
        }
}

// K3: fused softmax + context. Grid (4 col-chunks, 128 l-chunks).
// Every block recomputes softmax stats from scores[L] (cheap, L2-hot),
// then accumulates its 32-l x 256-col partial of context via atomicAdd,
// reading enc in bf16 (enc_bf) to halve this pass's traffic.
// Block (0,0) also writes the attn_weights output.
__global__ __launch_bounds__(256) void ctx_softmax_kernel(
        const float* __restrict__ scores,
        const unsigned short* __restrict__ enc_bf,
        float* __restrict__ context,
        float* __restrict__ attn_out) {
    __shared__ float smax[4];
    __shared__ float ssum[4];
    __shared__ float attn_l[32];
    int tid = threadIdx.x;
    int wid = tid >> 6, lane = tid & 63;
    // softmax stats over all L (16 values per thread)
    float4 s0 = ((const float4*)scores)[tid];
    float4 s1 = ((const float4*)scores)[256 + tid];
    float4 s2 = ((const float4*)scores)[512 + tid];
    float4 s3 = ((const float4*)scores)[768 + tid];
    float m = fmaxf(fmaxf(fmaxf(s0.x, s0.y), fmaxf(s0.z, s0.w)),
                    fmaxf(fmaxf(s1.x, s1.y), fmaxf(s1.z, s1.w)));
    m = fmaxf(m, fmaxf(fmaxf(s2.x, s2.y), fmaxf(s2.z, s2.w)));
    m = fmaxf(m, fmaxf(fmaxf(s3.x, s3.y), fmaxf(s3.z, s3.w)));
    for (int off = 32; off; off >>= 1) m = fmaxf(m, __shfl_xor(m, off));
    if (lane == 0) smax[wid] = m;
    __syncthreads();
    float gmax = fmaxf(fmaxf(smax[0], smax[1]), fmaxf(smax[2], smax[3]));
    float e = expf(s0.x - gmax) + expf(s0.y - gmax) + expf(s0.z - gmax) + expf(s0.w - gmax)
            + expf(s1.x - gmax) + expf(s1.y - gmax) + expf(s1.z - gmax) + expf(s1.w - gmax)
            + expf(s2.x - gmax) + expf(s2.y - gmax) + expf(s2.z - gmax) + expf(s2.w - gmax)
            + expf(s3.x - gmax) + expf(s3.y - gmax) + expf(s3.z - gmax) + expf(s3.w - gmax);
    e = wave_reduce(e);
    if (lane == 0) ssum[wid] = e;
    __syncthreads();
    float inv = 1.0f / (ssum[0] + ssum[1] + ssum[2] + ssum[3]);

    int l0 = blockIdx.y * 32;
    if (tid < 32) attn_l[tid] = expf(scores[l0 + tid] - gmax) * inv;
    __syncthreads();

    // attn_weights output (block (0,0) only)
    if (blockIdx.x == 0 && blockIdx.y == 0) {
        float4 a0 = make_float4(expf(s0.x - gmax) * inv, expf(s0.y - gmax) * inv,
                                expf(s0.z - gmax) * inv, expf(s0.w - gmax) * inv);
        float4 a1 = make_float4(expf(s1.x - gmax) * inv, expf(s1.y - gmax) * inv,
                                expf(s1.z - gmax) * inv, expf(s1.w - gmax) * inv);
        float4 a2 = make_float4(expf(s2.x - gmax) * inv, expf(s2.y - gmax) * inv,
                                expf(s2.z - gmax) * inv, expf(s2.w - gmax) * inv);
        float4 a3 = make_float4(expf(s3.x - gmax) * inv, expf(s3.y - gmax) * inv,
                                expf(s3.z - gmax) * inv, expf(s3.w - gmax) * inv);
        ((float4*)attn_out)[tid] = a0;
        ((float4*)attn_out)[256 + tid] = a1;
        ((float4*)attn_out)[512 + tid] = a2;
        ((float4*)attn_out)[768 + tid] = a3;
    }

    int col = blockIdx.x * 256 + tid;
    float acc = 0.f;
#pragma unroll 4
    for (int l = 0; l < 32; l++)
        acc += attn_l[l] * bf16_to_f32(enc_bf[(size_t)(l0 + l) * H + col]);
    atomicAdd(&context[col], acc);
}

// K4: x[j] = relu( [context; emb[token]] . cW[j,:] + cb[j] ), one wave per j.
__global__ void combine_kernel(const float* __restrict__ context,
                               const int* __restrict__ token,
                               const float* __restrict__ emb,
                               const float* __restrict__ cW,
                               const float* __restrict__ cb,
                               float* __restrict__ xvec) {
    int wave = (blockIdx.x * blockDim.x + threadIdx.x) >> 6;
    int lane = threadIdx.x & 63;
    if (wave >= H) return;
    const float4* row = (const float4*)(cW + (size_t)wave * 2 * H);
    const float4* cv = (const float4*)context;
    const float4* ev = (const float4*)(emb + (size_t)token[0] * H);
    float acc = 0.f;
#pragma unroll
    for (int i = 0; i < 4; i++) {
        int idx = i * 64 + lane;
        acc += dot4(row[idx], cv[idx]);
        acc += dot4(row[256 + idx], ev[idx]);
    }
    acc = wave_reduce(acc);
    if (lane == 0) xvec[wave] = fmaxf(acc + cb[wave], 0.f);
}

// K5: GRU cell, one wave per hidden unit j. Only the 3 gi dots remain here
// (gh precomputed in prep) -> 12 MB instead of 24 MB on the critical path.
__global__ void gru_kernel(const float* __restrict__ xvec,
                           const float* __restrict__ hprev,
                           const float* __restrict__ w_ih,
                           const float* __restrict__ b_ih,
                           const float* __restrict__ gh,
                           const float* __restrict__ context,
                           float* __restrict__ hnew_out,   // out + V
                           float* __restrict__ ovec) {
    int j = (blockIdx.x * blockDim.x + threadIdx.x) >> 6;
    int lane = threadIdx.x & 63;
    if (j >= H) return;
    const float4* xv = (const float4*)xvec;
    float a0 = 0.f, a1 = 0.f, a2 = 0.f;
#pragma unroll
    for (int i = 0; i < 4; i++) {
        int idx = i * 64 + lane;
        float4 x4 = xv[idx];
        a0 += dot4(((const float4*)(w_ih + (size_t)j * H))[idx], x4);
        a1 += dot4(((const float4*)(w_ih + (size_t)(H + j) * H))[idx], x4);
        a2 += dot4(((const float4*)(w_ih + (size_t)(2 * H + j) * H))[idx], x4);
    }
    a0 = wave_reduce(a0); a1 = wave_reduce(a1); a2 = wave_reduce(a2);
    if (lane == 0) {
        float ir = a0 + b_ih[j], iz = a1 + b_ih[H + j], inn = a2 + b_ih[2 * H + j];
        float r = 1.f / (1.f + expf(-(ir + gh[j])));
        float z = 1.f / (1.f + expf(-(iz + gh[H + j])));
        float n = tanhf(inn + r * gh[2 * H + j]);
        float hp = hprev[j];
        float hval = (1.f - z) * n + z * hp;
        hnew_out[j] = hval;
        ovec[j] = context[j] + hval;
    }
}

// K6: logits GEMV, 4 rows per wave (16 in-flight 16B loads per lane).
__global__ __launch_bounds__(256) void logits_kernel(
        const float* __restrict__ ovec,
        const float* __restrict__ outW,
        const float* __restrict__ outb,
        float* __restrict__ out) {
    int wave = (blockIdx.x * blockDim.x + threadIdx.x) >> 6;
    int lane = threadIdx.x & 63;
    int i0 = wave * 4;
    if (i0 >= V) return;
    const float4* ov = (const float4*)ovec;
    float4 o4[4];
#pragma unroll
    for (int t = 0; t < 4; t++) o4[t] = ov[t * 64 + lane];
    float acc0 = 0.f, acc1 = 0.f, acc2 = 0.f, acc3 = 0.f;
    const float4* row0 = (const float4*)(outW + (size_t)i0 * H);
    const float4* row1 = row0 + 256;
    const float4* row2 = row0 + 512;
    const float4* row3 = row0 + 768;
#pragma unroll
    for (int t = 0; t < 4; t++) {
        int idx = t * 64 + lane;
        acc0 += dot4(row0[idx], o4[t]);
        acc1 += dot4(row1[idx], o4[t]);
        acc2 += dot4(row2[idx], o4[t]);
        acc3 += dot4(row3[idx], o4[t]);
    }
    acc0 = wave_reduce(acc0);
    acc1 = wave_reduce(acc1);
    acc2 = wave_reduce(acc2);
    acc3 = wave_reduce(acc3);
    if (lane == 0) {
        out[i0] = acc0 + outb[i0];
        out[i0 + 1] = acc1 + outb[i0 + 1];
        out[i0 + 2] = acc2 + outb[i0 + 2];
        out[i0 + 3] = acc3 + outb[i0 + 3];
    }
}

extern "C" void kernel_launch(void* const* d_in, const int* in_sizes, int n_in,
                              void* d_out, int out_size, void* d_ws, size_t ws_size,
                              hipStream_t stream) {
    const int* token = (const int*)d_in[0];
    const float* hidden = (const float*)d_in[1];   // (1,1,H) == hprev == h0
    const float* enc = (const float*)d_in[2];
    const float* emb = (const float*)d_in[3];
    const float* wW = (const float*)d_in[4];
    const float* wb = (const float*)d_in[5];
    const float* uW = (const float*)d_in[6];
    const float* ub = (const float*)d_in[7];
    const float* vW = (const float*)d_in[8];
    const float* cW = (const float*)d_in[9];
    const float* cb = (const float*)d_in[10];
    const float* w_ih = (const float*)d_in[11];
    const float* b_ih = (const float*)d_in[12];
    const float* w_hh = (const float*)d_in[13];
    const float* b_hh = (const float*)d_in[14];
    const float* outW = (const float*)d_in[15];
    const float* outb = (const float*)d_in[16];
    float* out = (float*)d_out;

    char* ws = (char*)d_ws;
    unsigned short* enc_bf = (unsigned short*)ws;                         // 8 MiB
    unsigned short* u_bf = (unsigned short*)(ws + (size_t)L * H * 2);     // 2 MiB
    float* whv = (float*)(ws + (size_t)L * H * 2 + (size_t)H * H * 2);
    float* gh = whv + H;                     // 3H
    float* scores = gh + 3 * H;              // L floats (atomicAdd target)
    float* context = scores + L;             // H (zeroed by scores_kernel)
    float* xvec = context + H;               // H
    float* ovec = xvec + H;                  // H

    prep_kernel<<<1280, 256, 0, stream>>>(enc, uW, hidden, wW, wb, ub, w_hh, b_hh,
                                          enc_bf, u_bf, whv, gh, scores);
    scores_kernel<<<dim3(64, 8), 256, 0, stream>>>(enc_bf, u_bf, whv, vW, scores, context);
    ctx_softmax_kernel<<<dim3(4, 128), 256, 0, stream>>>(scores, enc_bf, context, out + V + H);
    combine_kernel<<<256, 256, 0, stream>>>(context, token, emb, cW, cb, xvec);
    gru_kernel<<<256, 256, 0, stream>>>(xvec, hidden, w_ih, b_ih, gh,
                                        context, out + V, ovec);
    logits_kernel<<<2000, 256, 0, stream>>>(ovec, outW, outb, out);
}